// Round 11
// baseline (1263.135 us; speedup 1.0000x reference)
//
#include <hip/hip_runtime.h>
#include <hip/hip_bf16.h>

#define K 5
#define F 64
#define EMBD 200
#define HID 256
#define NH 3
#define NL 3
#define CB 8            // crystals per block for POOL kernels
#define NB (CB * K)     // 40 nodes per pool block

// layer kernel: block-cooperative, 12 crystals / block
#define CPB 12          // crystals per block
#define NPB 60          // nodes per block (4 M-tiles of 16, rows 60-63 pad)
#define EPB 300         // edges per block (19 edge-tiles of 16)

typedef _Float16 half8 __attribute__((ext_vector_type(8)));
typedef float f32x4 __attribute__((ext_vector_type(4)));

__device__ __forceinline__ float lrelu(float v) { return v >= 0.f ? v : 0.01f * v; }

__device__ __forceinline__ half8 lrelu8(half8 t) {
    half8 z = 0;
    half8 p = __builtin_elementwise_max(t, z);
    half8 n = __builtin_elementwise_min(t, z);
    return p + n * (_Float16)0.01f;
}

// ---- swizzled-weight element counts (fp16) ----
#define W1SW_ELEMS 589824    // 9 lh * 2 net * 2 half * 4 chunk * 4 nt * 2 ks * 64 * 8
#define W2SW_ELEMS 147456    // 9 lh * 8 ks2 * 4 nt * 64 * 8
#define CW1_ELEMS   98304    // 3 h * 2 net * 4 chunk * 4 nt * 2 ks * 64 * 8
#define CW2_ELEMS   49152    // 3 h * 8 ks2 * 4 nt * 64 * 8
#define WALL_ELEMS (W1SW_ELEMS + W2SW_ELEMS + CW1_ELEMS + CW2_ELEMS)  // 884736
#define BIAS_ELEMS 6912      // 9 lh * 3 arrays{gb1,mb1,gW2} * 256, fp16

// per-layer (fallback) sizes
#define W1L_ELEMS 196608
#define W2L_ELEMS 49152
#define BIASL_ELEMS 2304     // 3 h * 3 * 256

// ---------------------------------------------------------------------------
// Fast path: swizzle ALL weights + pack fp16 biases.
// ---------------------------------------------------------------------------
__global__ __launch_bounds__(256)
void prep_all(const float* __restrict__ gW1, const float* __restrict__ mW1,
              const float* __restrict__ mW2,
              const float* __restrict__ cgW1, const float* __restrict__ cmW1,
              const float* __restrict__ cmW2,
              const float* __restrict__ gb1, const float* __restrict__ mb1,
              const float* __restrict__ gW2,
              _Float16* __restrict__ Wall)
{
    int tid = blockIdx.x * 256 + threadIdx.x;
    if (tid >= WALL_ELEMS + BIAS_ELEMS) return;
    float v;
    if (tid < W1SW_ELEMS) {
        int j = tid & 7, lane = (tid >> 3) & 63;
        int r1 = tid >> 9;                       // [lh][net][half][chunk][nt][ks]
        int ks = r1 & 1, nt = (r1 >> 1) & 3, chunk = (r1 >> 3) & 3;
        int half = (r1 >> 5) & 1, net = (r1 >> 6) & 1, lh = r1 >> 7;   // 0..8
        int q = lane >> 4, n16 = lane & 15;
        const float* src = net ? mW1 : gW1;
        v = src[((size_t)lh * 128 + half * 64 + ks * 32 + q * 8 + j) * 256
                + chunk * 64 + nt * 16 + n16];
    } else if (tid < W1SW_ELEMS + W2SW_ELEMS) {
        int t2 = tid - W1SW_ELEMS;
        int j = t2 & 7, lane = (t2 >> 3) & 63;
        int r1 = t2 >> 9;                        // [lh][ks2][nt]
        int nt = r1 & 3, ks2 = (r1 >> 2) & 7, lh = r1 >> 5;            // 0..8
        int q = lane >> 4, n16 = lane & 15;
        v = mW2[((size_t)lh * 256 + ks2 * 32 + q * 8 + j) * 64 + nt * 16 + n16];
    } else if (tid < W1SW_ELEMS + W2SW_ELEMS + CW1_ELEMS) {
        int t2 = tid - (W1SW_ELEMS + W2SW_ELEMS);
        int j = t2 & 7, lane = (t2 >> 3) & 63;
        int r1 = t2 >> 9;                        // [h][net][chunk][nt][ks]
        int ks = r1 & 1, nt = (r1 >> 1) & 3, chunk = (r1 >> 3) & 3;
        int net = (r1 >> 5) & 1, h = r1 >> 6;                          // 0..2
        int q = lane >> 4, n16 = lane & 15;
        const float* src = net ? cmW1 : cgW1;
        v = src[((size_t)h * 64 + ks * 32 + q * 8 + j) * 256
                + chunk * 64 + nt * 16 + n16];
    } else if (tid < WALL_ELEMS) {
        int t2 = tid - (W1SW_ELEMS + W2SW_ELEMS + CW1_ELEMS);
        int j = t2 & 7, lane = (t2 >> 3) & 63;
        int r1 = t2 >> 9;                        // [h][ks2][nt]
        int nt = r1 & 3, ks2 = (r1 >> 2) & 7, h = r1 >> 5;             // 0..2
        int q = lane >> 4, n16 = lane & 15;
        v = cmW2[((size_t)h * 256 + ks2 * 32 + q * 8 + j) * 64 + nt * 16 + n16];
    } else {
        int t3 = tid - WALL_ELEMS;               // [lh][arr][u]
        int u = t3 & 255;
        int arr = (t3 >> 8) % 3;
        int lh = t3 / 768;
        const float* src = arr == 0 ? gb1 : (arr == 1 ? mb1 : gW2);
        v = src[(size_t)lh * 256 + u];
    }
    Wall[tid] = (_Float16)v;
}

// ---------------------------------------------------------------------------
// Fallback: per-layer prep into d_out scratch.
// ---------------------------------------------------------------------------
__global__ __launch_bounds__(256)
void prep_layer(const float* __restrict__ gW1, const float* __restrict__ mW1,
                const float* __restrict__ mW2,
                const float* __restrict__ gb1, const float* __restrict__ mb1,
                const float* __restrict__ gW2,
                _Float16* __restrict__ W1sw, _Float16* __restrict__ W2sw,
                _Float16* __restrict__ Bf, int l)
{
    int tid = blockIdx.x * 256 + threadIdx.x;
    if (tid < W1L_ELEMS) {
        int j = tid & 7, lane = (tid >> 3) & 63;
        int r1 = tid >> 9;
        int ks = r1 & 1, nt = (r1 >> 1) & 3, chunk = (r1 >> 3) & 3;
        int half = (r1 >> 5) & 1, net = (r1 >> 6) & 1, hh = r1 >> 7;
        int q = lane >> 4, n16 = lane & 15;
        const float* src = net ? mW1 : gW1;
        float v = src[((size_t)(l * NH + hh) * 128 + half * 64 + ks * 32 + q * 8 + j) * 256
                      + chunk * 64 + nt * 16 + n16];
        W1sw[tid] = (_Float16)v;
    } else if (tid < W1L_ELEMS + W2L_ELEMS) {
        int t2 = tid - W1L_ELEMS;
        int j = t2 & 7, lane = (t2 >> 3) & 63;
        int r1 = t2 >> 9;
        int nt = r1 & 3, ks2 = (r1 >> 2) & 7, hh = r1 >> 5;
        int q = lane >> 4, n16 = lane & 15;
        float v = mW2[((size_t)(l * NH + hh) * 256 + ks2 * 32 + q * 8 + j) * 64
                      + nt * 16 + n16];
        W2sw[t2] = (_Float16)v;
    } else if (tid < W1L_ELEMS + W2L_ELEMS + BIASL_ELEMS) {
        int t3 = tid - (W1L_ELEMS + W2L_ELEMS);
        int u = t3 & 255;
        int arr = (t3 >> 8) % 3;
        int hh = t3 / 768;
        const float* src = arr == 0 ? gb1 : (arr == 1 ? mb1 : gW2);
        Bf[t3] = (_Float16)src[(size_t)(l * NH + hh) * 256 + u];
    }
}

// ---------------------------------------------------------------------------
// Embedding
// ---------------------------------------------------------------------------
__global__ __launch_bounds__(64)
void embed_kernel(const float* __restrict__ fea, const float* __restrict__ W,
                  const float* __restrict__ b, const float* __restrict__ wts,
                  float* __restrict__ x)
{
    int n = blockIdx.x;
    int o = threadIdx.x;
    __shared__ float fs[EMBD];
    for (int e = o; e < EMBD; e += 64) fs[e] = fea[n * EMBD + e];
    __syncthreads();
    if (o < F - 1) {
        float acc = b[o];
#pragma unroll 8
        for (int e = 0; e < EMBD; ++e) acc += fs[e] * W[e * (F - 1) + o];
        x[n * F + o] = acc;
    } else {
        x[n * F + F - 1] = wts[n];
    }
}

// ---------------------------------------------------------------------------
// One graph layer — block-cooperative. 12 crystals/block, 4 waves.
// Stage-1: wave w computes net-half w for ALL 4 M-tiles (8 B-loads -> 32 MFMA,
// true M-dimension work sharing). Consume: wave w owns edge-tiles w,w+4,...
// Loads prefetched before each barrier so the barrier's vmcnt-drain overlaps
// wave-arrival skew. No occupancy pin (round-7 spill lesson).
// ---------------------------------------------------------------------------
__global__ __launch_bounds__(256)
void layer_coop(float* __restrict__ x,
                const _Float16* __restrict__ W1sw,
                const _Float16* __restrict__ W2sw,
                const _Float16* __restrict__ Bf,     // [lhw][3][256] fp16 biases
                const float* __restrict__ gb2v, const float* __restrict__ mb2,
                const float* __restrict__ gpw, const float* __restrict__ wts,
                int l, int lhw0, int Ntot)
{
    __shared__ __align__(16) char PQraw[40128];   // max(4*64*72, 304*66)*2
    __shared__ float gateS[304];
    __shared__ float anormS[304];
    __shared__ float wpowS[64];

    _Float16 (*PQ)[64][72] = (_Float16 (*)[64][72])PQraw;  // [4 hf][64 rows][72]
    _Float16 (*msgL)[66]   = (_Float16 (*)[66])PQraw;      // [304][66], aliases PQ

    const int t = threadIdx.x, w = t >> 6, lane = t & 63;
    const int q = lane >> 4, m16 = lane & 15;
    const int node0 = blockIdx.x * NPB;

    // ---- A-fragments: 4 M-tiles x 2 k-slices, fp16, loaded once ----
    half8 A[4][2];
#pragma unroll
    for (int Mt = 0; Mt < 4; ++Mt) {
        int arow = node0 + Mt * 16 + m16;
        if (arow > Ntot - 1) arow = Ntot - 1;     // clamp pad rows (finite)
        const float* xr = x + (size_t)arow * F;
#pragma unroll
        for (int ks = 0; ks < 2; ++ks) {
            float4 f0 = *(const float4*)(xr + ks * 32 + q * 8);
            float4 f1 = *(const float4*)(xr + ks * 32 + q * 8 + 4);
            half8 a;
            a[0] = (_Float16)f0.x; a[1] = (_Float16)f0.y;
            a[2] = (_Float16)f0.z; a[3] = (_Float16)f0.w;
            a[4] = (_Float16)f1.x; a[5] = (_Float16)f1.y;
            a[6] = (_Float16)f1.z; a[7] = (_Float16)f1.w;
            A[Mt][ks] = a;
        }
    }

    // ---- edge-tile ownership: wave w owns tiles {w, w+4, ..} (19 tiles) ----
    const int nem = (w == 3) ? 4 : 5;
    int iR[5], jR[5];
#pragma unroll
    for (int r = 0; r < 5; ++r) {
        int e = (w + 4 * r) * 16 + m16;
        if (r < nem && e < EPB) {
            int cl = e / 25, rm = e % 25;
            iR[r] = cl * K + rm / K;
            jR[r] = cl * K + rm % K;
        } else { iR[r] = 63; jR[r] = 63; }        // pad row (finite junk)
    }

    if (w == 3 && lane < 4) anormS[EPB + lane] = 0.f;   // pad anorm slots 300..303

    float oacc[15];
#pragma unroll
    for (int n = 0; n < 15; ++n) oacc[n] = 0.f;
    int vn = Ntot - (node0 + w * 15);
    vn = vn < 0 ? 0 : (vn > 15 ? 15 : vn);

    for (int h = 0; h < NH; ++h) {
        const int lh = l * NH + h, lhw = lhw0 + h;

        if (lane < 15) {
            int wi = node0 + w * 15 + lane;
            if (wi > Ntot - 1) wi = Ntot - 1;
            wpowS[w * 15 + lane] = powf(wts[wi], gpw[lh]);
        }

        f32x4 acc2[5][4];
#pragma unroll
        for (int r = 0; r < 5; ++r)
#pragma unroll
            for (int nt = 0; nt < 4; ++nt) acc2[r][nt] = (f32x4){0.f, 0.f, 0.f, 0.f};
        float gacc[5] = {0.f, 0.f, 0.f, 0.f, 0.f};

        for (int c = 0; c < 4; ++c) {
            // ---- prefetch stage-1 B frags (drained by the barrier below) ----
            half8 B1[8];
            {
                const _Float16* Wb = W1sw + ((size_t)lhw * 4 + w) * 16384 + c * 4096;
#pragma unroll
                for (int f = 0; f < 8; ++f)
                    B1[f] = *(const half8*)(Wb + (f * 64 + lane) * 8);
            }
            __syncthreads();   // prev consume/aggregate done; B1 arrived

            // ---- stage-1: net-half w, all 4 M-tiles (Mt-sequential: small accS) ----
#pragma unroll
            for (int Mt = 0; Mt < 4; ++Mt) {
                f32x4 accS[4];
#pragma unroll
                for (int nt = 0; nt < 4; ++nt) accS[nt] = (f32x4){0.f, 0.f, 0.f, 0.f};
#pragma unroll
                for (int nt = 0; nt < 4; ++nt)
#pragma unroll
                    for (int ks = 0; ks < 2; ++ks)
                        accS[nt] = __builtin_amdgcn_mfma_f32_16x16x32_f16(
                            A[Mt][ks], B1[nt * 2 + ks], accS[nt], 0, 0, 0);
#pragma unroll
                for (int nt = 0; nt < 4; ++nt)
#pragma unroll
                    for (int rg = 0; rg < 4; ++rg)
                        PQ[w][Mt * 16 + q * 4 + rg][nt * 16 + m16] =
                            (_Float16)accS[nt][rg];
            }

            // ---- prefetch B2 + fp16 biases (drained by barrier below) ----
            half8 B2[8];
            {
                const _Float16* W2b = W2sw + ((size_t)lhw * 8 + c * 2) * 2048;
#pragma unroll
                for (int f = 0; f < 8; ++f)
                    B2[f] = *(const half8*)(W2b + ((size_t)f * 64 + lane) * 8);
            }
            half8 bg8[2], bm8[2];
            float wgf[2][8];
            {
                const _Float16* Bp = Bf + (size_t)lhw * 768;
#pragma unroll
                for (int ks = 0; ks < 2; ++ks) {
                    const int off = c * 64 + ks * 32 + q * 8;
                    bg8[ks] = *(const half8*)(Bp + off);
                    bm8[ks] = *(const half8*)(Bp + 256 + off);
                    half8 wg8 = *(const half8*)(Bp + 512 + off);
#pragma unroll
                    for (int jj = 0; jj < 8; ++jj) wgf[ks][jj] = (float)wg8[jj];
                }
            }
            __syncthreads();   // PQ ready; B2/biases arrived

            // ---- consume: gate partial + hm A-frags + GEMM2 ----
            for (int r = 0; r < nem; ++r) {
                half8 af[2];
#pragma unroll
                for (int ks = 0; ks < 2; ++ks) {
                    const int ub = ks * 32 + q * 8;
                    half8 pg = *(const half8*)&PQ[0][iR[r]][ub];
                    half8 qg = *(const half8*)&PQ[1][jR[r]][ub];
                    half8 pm = *(const half8*)&PQ[2][iR[r]][ub];
                    half8 qm = *(const half8*)&PQ[3][jR[r]][ub];
                    half8 tg = lrelu8(pg + qg + bg8[ks]);
#pragma unroll
                    for (int jj = 0; jj < 8; ++jj)
                        gacc[r] += (float)tg[jj] * wgf[ks][jj];
                    af[ks] = lrelu8(pm + qm + bm8[ks]);
                }
#pragma unroll
                for (int nt = 0; nt < 4; ++nt)
#pragma unroll
                    for (int ks = 0; ks < 2; ++ks)
                        acc2[r][nt] = __builtin_amdgcn_mfma_f32_16x16x32_f16(
                            af[ks], B2[ks * 4 + nt], acc2[r][nt], 0, 0, 0);
            }
        }

        // ---- gate reduce across quads, write gateS[edge] ----
        const float gb2s = gb2v[lh];
        for (int r = 0; r < nem; ++r) {
            float g = gacc[r];
            g += __shfl_xor(g, 16);
            g += __shfl_xor(g, 32);
            if (q == 0) gateS[(w + 4 * r) * 16 + m16] = g + gb2s;
        }
        __syncthreads();   // gates (cross-wave) + wpow ready

        // ---- segment softmax: wave w handles nodes w*15..w*15+14 ----
        if (lane < 15) {
            int n = w * 15 + lane;
            int cl = n / K;
            int base = cl * 25 + (n % K) * K;
            float gg[K], mx = -1e30f;
#pragma unroll
            for (int jj = 0; jj < K; ++jj) {
                gg[jj] = gateS[base + jj];
                mx = fmaxf(mx, gg[jj]);
            }
            float s = 0.f, wv[K];
#pragma unroll
            for (int jj = 0; jj < K; ++jj) {
                wv[jj] = wpowS[cl * K + jj] * expf(gg[jj] - mx);
                s += wv[jj];
            }
            float inv = 1.f / (s + 1e-10f) * (1.f / 3.f);   // fold head mean
#pragma unroll
            for (int jj = 0; jj < K; ++jj) anormS[base + jj] = wv[jj] * inv;
        }
        __syncthreads();   // anorm ready (gateS dead -> msgL may clobber PQraw)

        // ---- weighted msg -> msgL (PQ dead) ----
        float b2v[4];
#pragma unroll
        for (int nt = 0; nt < 4; ++nt) b2v[nt] = mb2[(size_t)lh * F + nt * 16 + m16];
        for (int r = 0; r < nem; ++r) {
            int et = w + 4 * r;
            f32x4 an = *(const f32x4*)&anormS[et * 16 + q * 4];
#pragma unroll
            for (int nt = 0; nt < 4; ++nt)
#pragma unroll
                for (int rg = 0; rg < 4; ++rg) {
                    float v = (acc2[r][nt][rg] + b2v[nt]) * an[rg];
                    msgL[et * 16 + q * 4 + rg][nt * 16 + m16] = (_Float16)v;
                }
        }
        __syncthreads();   // msgL ready (cross-wave)

        // ---- aggregate: wave w sums its 15 nodes, lane = output col ----
#pragma unroll
        for (int idx = 0; idx < 15; ++idx) {
            int n = w * 15 + idx;
            int base = (n / K) * 25 + (n % K) * K;
            float s = 0.f;
#pragma unroll
            for (int jj = 0; jj < K; ++jj) s += (float)msgL[base + jj][lane];
            oacc[idx] += s;
        }
        // next head's first barrier protects msgL until all waves aggregated
    }

    // ---- residual + write back ----
#pragma unroll
    for (int idx = 0; idx < 15; ++idx) {
        if (idx < vn) {
            size_t gi = (size_t)(node0 + w * 15 + idx) * F + lane;
            x[gi] = oacc[idx] + x[gi];
        }
    }
}

// ---------------------------------------------------------------------------
// MFMA pool (round-5 proven)
// ---------------------------------------------------------------------------
__global__ __launch_bounds__(256)
void pool_mfma(const float* __restrict__ x,
               const _Float16* __restrict__ cW1sw,
               const _Float16* __restrict__ cW2sw,
               const float* __restrict__ cgb1, const float* __restrict__ cgb2v,
               const float* __restrict__ cmb1, const float* __restrict__ cmb2,
               const float* __restrict__ cgW2, const float* __restrict__ cpw,
               const float* __restrict__ wts, float* __restrict__ out)
{
    __shared__ __align__(16) _Float16 xh[48][72];
    __shared__ __align__(16) char PQraw[2 * 48 * 72 * 2];
    __shared__ float outacc[CB * F];
    __shared__ float b1gS[HID], b1mS[HID], w2gS[HID], b2mS[F];
    __shared__ float gateS[48], anormS[48], wpowS[48];

    _Float16 (*P)[48][72] = (_Float16 (*)[48][72])PQraw;
    _Float16 (*msgW)[72]  = (_Float16 (*)[72])PQraw;

    const int t = threadIdx.x, w = t >> 6, lane = t & 63;
    const int quad = lane >> 4, m16 = lane & 15;
    const int node0 = blockIdx.x * NB;

    for (int d = t; d < 48 * 64; d += 256) {
        int r = d >> 6, cc = d & 63;
        float v = (r < NB) ? x[(size_t)(node0 + r) * F + cc] : 0.f;
        xh[r][cc] = (_Float16)v;
    }
    for (int d = t; d < CB * F; d += 256) outacc[d] = 0.f;
    __syncthreads();

    half8 A[3][2];
#pragma unroll
    for (int Mt = 0; Mt < 3; ++Mt)
#pragma unroll
        for (int ks = 0; ks < 2; ++ks)
            A[Mt][ks] = *(const half8*)&xh[Mt * 16 + m16][ks * 32 + quad * 8];

    const int net = w >> 1, ntp = w & 1;

    for (int h = 0; h < NH; ++h) {
        if (t < HID) {
            b1gS[t] = cgb1[(size_t)h * HID + t];
            b1mS[t] = cmb1[(size_t)h * HID + t];
            w2gS[t] = cgW2[(size_t)h * HID + t];
        }
        if (t < F)  b2mS[t] = cmb2[(size_t)h * F + t];
        if (t < NB) wpowS[t] = powf(wts[node0 + t], cpw[h]);
        const float gb2s = cgb2v[h];

        f32x4 acc2[4];
#pragma unroll
        for (int nt = 0; nt < 4; ++nt) acc2[nt] = (f32x4){0.f, 0.f, 0.f, 0.f};
        float gacc = 0.f;

        for (int chunk = 0; chunk < 4; ++chunk) {
            {
                f32x4 accS[3][2];
#pragma unroll
                for (int Mt = 0; Mt < 3; ++Mt)
#pragma unroll
                    for (int n2 = 0; n2 < 2; ++n2) accS[Mt][n2] = (f32x4){0.f, 0.f, 0.f, 0.f};
                const _Float16* Wb = cW1sw + ((size_t)(h * 2 + net) * 4 + chunk) * 4096;
#pragma unroll
                for (int n2 = 0; n2 < 2; ++n2) {
                    int nt = ntp * 2 + n2;
#pragma unroll
                    for (int ks = 0; ks < 2; ++ks) {
                        half8 B = *(const half8*)(Wb + ((nt * 2 + ks) * 64 + lane) * 8);
#pragma unroll
                        for (int Mt = 0; Mt < 3; ++Mt)
                            accS[Mt][n2] = __builtin_amdgcn_mfma_f32_16x16x32_f16(
                                A[Mt][ks], B, accS[Mt][n2], 0, 0, 0);
                    }
                }
#pragma unroll
                for (int Mt = 0; Mt < 3; ++Mt)
#pragma unroll
                    for (int n2 = 0; n2 < 2; ++n2)
#pragma unroll
                        for (int rg = 0; rg < 4; ++rg)
                            P[net][Mt * 16 + quad * 4 + rg][(ntp * 2 + n2) * 16 + m16] =
                                (_Float16)accS[Mt][n2][rg];
            }
            __syncthreads();

            if (w < 3) {
                half8 af[2];
#pragma unroll
                for (int ks = 0; ks < 2; ++ks) {
                    const int ub = ks * 32 + quad * 8;
                    half8 pg = *(const half8*)&P[0][w * 16 + m16][ub];
                    half8 pm = *(const half8*)&P[1][w * 16 + m16][ub];
#pragma unroll
                    for (int j = 0; j < 8; ++j) {
                        int u = chunk * 64 + ub + j;
                        float gh = lrelu((float)pg[j] + b1gS[u]);
                        gacc += gh * w2gS[u];
                        float hv = lrelu((float)pm[j] + b1mS[u]);
                        af[ks][j] = (_Float16)hv;
                    }
                }
                const _Float16* W2b = cW2sw + (size_t)h * 16384 + chunk * 4096;
#pragma unroll
                for (int nt = 0; nt < 4; ++nt)
#pragma unroll
                    for (int ks = 0; ks < 2; ++ks) {
                        half8 B = *(const half8*)(W2b + ((size_t)(ks * 4 + nt) * 64 + lane) * 8);
                        acc2[nt] = __builtin_amdgcn_mfma_f32_16x16x32_f16(
                            af[ks], B, acc2[nt], 0, 0, 0);
                    }
            }
            __syncthreads();
        }

        if (w < 3) {
            float g = gacc;
            g += __shfl_xor(g, 16);
            g += __shfl_xor(g, 32);
            if (quad == 0) gateS[w * 16 + m16] = g + gb2s;
        }
        __syncthreads();

        if (t < CB) {
            float mx = -1e30f;
#pragma unroll
            for (int j = 0; j < K; ++j) mx = fmaxf(mx, gateS[t * K + j]);
            float s = 0.f, wv[K];
#pragma unroll
            for (int j = 0; j < K; ++j) {
                wv[j] = wpowS[t * K + j] * expf(gateS[t * K + j] - mx);
                s += wv[j];
            }
            float inv = 1.f / (s + 1e-10f) * (1.f / 3.f);
#pragma unroll
            for (int j = 0; j < K; ++j) anormS[t * K + j] = wv[j] * inv;
        }
        __syncthreads();

        if (w < 3) {
#pragma unroll
            for (int nt = 0; nt < 4; ++nt)
#pragma unroll
                for (int rg = 0; rg < 4; ++rg) {
                    int row = w * 16 + quad * 4 + rg;
                    float a = (row < NB) ? anormS[row] : 0.f;
                    float v = (acc2[nt][rg] + b2mS[nt * 16 + m16]) * a;
                    msgW[row][nt * 16 + m16] = (_Float16)v;
                }
        }
        __syncthreads();

        for (int d = t; d < CB * F; d += 256) {
            int cr = d >> 6, o = d & 63;
            float s = 0.f;
#pragma unroll
            for (int j = 0; j < K; ++j) s += (float)msgW[cr * K + j][o];
            outacc[d] += s;
        }
        __syncthreads();
    }

    for (int d = t; d < CB * F; d += 256)
        out[(size_t)blockIdx.x * (CB * F) + d] = outacc[d];
}

// ---------------------------------------------------------------------------
// Fallback fp32 pool (round-4 proven)
// ---------------------------------------------------------------------------
__global__ __launch_bounds__(256)
void pool_kernel(const float* __restrict__ x,
                 const float* __restrict__ cgW1, const float* __restrict__ cgb1,
                 const float* __restrict__ cgW2, const float* __restrict__ cgb2,
                 const float* __restrict__ cmW1, const float* __restrict__ cmb1,
                 const float* __restrict__ cmW2, const float* __restrict__ cmb2,
                 const float* __restrict__ cpw, const float* __restrict__ wts,
                 float* __restrict__ out)
{
    __shared__ float xs[K * F];
    __shared__ float hmS[K][HID];
    __shared__ float msgS[K][F];
    __shared__ float outacc[F];
    __shared__ float b1g[HID], b1m[HID], w2g[HID];
    __shared__ float b2mS[F];
    __shared__ float gpart[K][2];
    __shared__ float gate_s[K];
    __shared__ float anorm[K];
    __shared__ float wn[K], wpow[K];

    const int c = blockIdx.x;
    const int t = threadIdx.x;
    const int wave = t >> 6, lane = t & 63;

    for (int d = t; d < K * F; d += 256) xs[d] = x[c * K * F + d];
    if (t < F) outacc[t] = 0.f;
    if (t < K) wn[t] = wts[c * K + t];
    __syncthreads();

    for (int h = 0; h < NH; ++h) {
        if (t < HID) {
            b1g[t] = cgb1[(size_t)h * HID + t];
            b1m[t] = cmb1[(size_t)h * HID + t];
            w2g[t] = cgW2[(size_t)h * HID + t];
        }
        if (t < F) b2mS[t] = cmb2[(size_t)h * F + t];
        if (t < K) wpow[t] = powf(wn[t], cpw[h]);
        __syncthreads();

        {
            const int grp = t >> 7;
            const int up  = t & 127;
            const float* Wb = (grp == 0 ? cgW1 : cmW1) + (size_t)h * F * HID;
            const float2* W2p = (const float2*)Wb;
            float acc[K][2];
#pragma unroll
            for (int i = 0; i < K; ++i) { acc[i][0] = 0.f; acc[i][1] = 0.f; }
            for (int k = 0; k < F; ++k) {
                float2 wv = W2p[k * (HID / 2) + up];
#pragma unroll
                for (int i = 0; i < K; ++i) {
                    float xv = xs[i * F + k];
                    acc[i][0] += xv * wv.x;
                    acc[i][1] += xv * wv.y;
                }
            }
            if (grp == 0) {
#pragma unroll
                for (int i = 0; i < K; ++i) {
                    float h0 = lrelu(acc[i][0] + b1g[2 * up]);
                    float h1 = lrelu(acc[i][1] + b1g[2 * up + 1]);
                    float part = h0 * w2g[2 * up] + h1 * w2g[2 * up + 1];
#pragma unroll
                    for (int s = 32; s; s >>= 1) part += __shfl_xor(part, s);
                    if (lane == 0) gpart[i][wave & 1] = part;
                }
            } else {
#pragma unroll
                for (int i = 0; i < K; ++i) {
                    hmS[i][2 * up]     = lrelu(acc[i][0] + b1m[2 * up]);
                    hmS[i][2 * up + 1] = lrelu(acc[i][1] + b1m[2 * up + 1]);
                }
            }
        }
        __syncthreads();
        if (t < K) gate_s[t] = cgb2[h] + gpart[t][0] + gpart[t][1];

        {
            const float2* W232 = (const float2*)(cmW2 + (size_t)h * HID * F);
            if (t < K * (F / 2)) {
                int i  = t >> 5;
                int op = t & 31;
                float a0 = b2mS[2 * op], a1 = b2mS[2 * op + 1];
#pragma unroll 8
                for (int u = 0; u < HID; ++u) {
                    float2 wv = W232[u * (F / 2) + op];
                    float hv = hmS[i][u];
                    a0 += hv * wv.x;
                    a1 += hv * wv.y;
                }
                msgS[i][2 * op]     = a0;
                msgS[i][2 * op + 1] = a1;
            }
        }
        __syncthreads();

        if (t == 0) {
            float mx = -1e30f;
#pragma unroll
            for (int i = 0; i < K; ++i) mx = fmaxf(mx, gate_s[i]);
            float wv[K], s = 0.f;
#pragma unroll
            for (int i = 0; i < K; ++i) {
                wv[i] = wpow[i] * expf(gate_s[i] - mx);
                s += wv[i];
            }
            float inv = 1.f / (s + 1e-10f);
#pragma unroll
            for (int i = 0; i < K; ++i) anorm[i] = wv[i] * inv;
        }
        __syncthreads();

        if (t < F) {
            float s = 0.f;
#pragma unroll
            for (int i = 0; i < K; ++i) s += anorm[i] * msgS[i][t];
            outacc[t] += s * (1.f / 3.f);
        }
        __syncthreads();
    }

    if (t < F) out[(size_t)c * F + t] = outacc[t];
}

// ---------------------------------------------------------------------------
extern "C" void kernel_launch(void* const* d_in, const int* in_sizes, int n_in,
                              void* d_out, int out_size, void* d_ws, size_t ws_size,
                              hipStream_t stream)
{
    const float* wts  = (const float*)d_in[0];
    const float* fea  = (const float*)d_in[1];
    const float* embW = (const float*)d_in[6];
    const float* embB = (const float*)d_in[7];
    const float* gW1  = (const float*)d_in[8];
    const float* gb1  = (const float*)d_in[9];
    const float* gW2  = (const float*)d_in[10];
    const float* gb2  = (const float*)d_in[11];
    const float* mW1  = (const float*)d_in[12];
    const float* mb1  = (const float*)d_in[13];
    const float* mW2  = (const float*)d_in[14];
    const float* mb2  = (const float*)d_in[15];
    const float* gpw  = (const float*)d_in[16];
    const float* cgW1 = (const float*)d_in[17];
    const float* cgb1 = (const float*)d_in[18];
    const float* cgW2 = (const float*)d_in[19];
    const float* cgb2 = (const float*)d_in[20];
    const float* cmW1 = (const float*)d_in[21];
    const float* cmb1 = (const float*)d_in[22];
    const float* cmW2 = (const float*)d_in[23];
    const float* cmb2 = (const float*)d_in[24];
    const float* cpw  = (const float*)d_in[25];

    const int N = in_sizes[0];   // 50000
    const int C = N / K;         // 10000
    const int layer_blocks = (C + CPB - 1) / CPB;   // 834 (tail guarded)

    float* x = (float*)d_ws;                       // [N,F] fp32, 12.8 MB
    const size_t xbytes = (size_t)N * F * 4;
    const size_t need = xbytes + (size_t)(WALL_ELEMS + BIAS_ELEMS) * 2;

    embed_kernel<<<N, 64, 0, stream>>>(fea, embW, embB, wts, x);

    if (ws_size >= need) {
        // ---- fast path ----
        _Float16* Wall  = (_Float16*)((char*)d_ws + xbytes);
        _Float16* W1sw  = Wall;
        _Float16* W2sw  = Wall + W1SW_ELEMS;
        _Float16* cW1sw = Wall + W1SW_ELEMS + W2SW_ELEMS;
        _Float16* cW2sw = Wall + W1SW_ELEMS + W2SW_ELEMS + CW1_ELEMS;
        _Float16* Bf    = Wall + WALL_ELEMS;

        prep_all<<<(WALL_ELEMS + BIAS_ELEMS + 255) / 256, 256, 0, stream>>>(
            gW1, mW1, mW2, cgW1, cmW1, cmW2, gb1, mb1, gW2, Wall);
        for (int l = 0; l < NL; ++l)
            layer_coop<<<layer_blocks, 256, 0, stream>>>(x, W1sw, W2sw, Bf,
                                                         gb2, mb2, gpw, wts,
                                                         l, l * NH, N);
        pool_mfma<<<C / CB, 256, 0, stream>>>(x, cW1sw, cW2sw,
                                              cgb1, cgb2, cmb1, cmb2, cgW2, cpw, wts,
                                              (float*)d_out);
    } else {
        // ---- fallback: per-layer prep into d_out scratch ----
        _Float16* W1sw = (_Float16*)d_out;
        _Float16* W2sw = (_Float16*)((char*)d_out + 393216);
        _Float16* Bf   = (_Float16*)((char*)d_out + 393216 + 98304);
        for (int l = 0; l < NL; ++l) {
            prep_layer<<<(W1L_ELEMS + W2L_ELEMS + BIASL_ELEMS + 255) / 256, 256, 0, stream>>>(
                gW1, mW1, mW2, gb1, mb1, gW2, W1sw, W2sw, Bf, l);
            layer_coop<<<layer_blocks, 256, 0, stream>>>(x, W1sw, W2sw, Bf,
                                                         gb2, mb2, gpw, wts,
                                                         l, 0, N);
        }
        pool_kernel<<<C, 256, 0, stream>>>(x, cgW1, cgb1, cgW2, cgb2,
                                           cmW1, cmb1, cmW2, cmb2, cpw, wts,
                                           (float*)d_out);
    }
}